// Round 1
// baseline (257.182 us; speedup 1.0000x reference)
//
#include <hip/hip_runtime.h>

typedef unsigned short u16;
typedef unsigned int u32;
typedef __bf16 bf16x8 __attribute__((ext_vector_type(8)));
typedef float f32x4 __attribute__((ext_vector_type(4)));
typedef u16 u16x8 __attribute__((ext_vector_type(8)));
typedef u16 u16x4 __attribute__((ext_vector_type(4)));

#define BB 4
#define NQ 4096
#define NKV 1024
#define QD 512
#define CD 768
#define NH 8
#define DH 64
#define DI 512

__device__ __forceinline__ u16 f2bf(float f) {
    u32 u = __float_as_uint(f);
    u = (u + 0x7fffu + ((u >> 16) & 1u)) >> 16;
    return (u16)u;
}

// ---------- weight transpose + f32->bf16: Wt[n][k] = bf16(W[k][n]) ----------
__global__ __launch_bounds__(256)
void k_transposeW(const float* __restrict__ W, u16* __restrict__ Wt, int K, int N) {
    __shared__ float tile[32][33];
    int kb = blockIdx.x * 32, nb = blockIdx.y * 32;
    int tx = threadIdx.x & 31, ty = threadIdx.x >> 5;  // ty 0..7
    for (int i = ty; i < 32; i += 8)
        tile[i][tx] = W[(size_t)(kb + i) * N + nb + tx];
    __syncthreads();
    for (int i = ty; i < 32; i += 8)
        Wt[(size_t)(nb + i) * K + kb + tx] = f2bf(tile[tx][i]);
}

// ---------- V transpose: Vt[(bh*64+d)*NKV + j] = KV[(b*NKV+j)*1024 + 512 + h*64 + d] ----------
__global__ __launch_bounds__(256)
void k_transposeV(const u16* __restrict__ KV, u16* __restrict__ Vt) {
    __shared__ u16 tile[32][33];
    int j0 = blockIdx.x * 32, d0 = blockIdx.y * 32, bh = blockIdx.z;
    int b = bh >> 3, h = bh & 7;
    int tx = threadIdx.x & 31, ty = threadIdx.x >> 5;
    for (int i = ty; i < 32; i += 8)
        tile[i][tx] = KV[(size_t)(b * NKV + j0 + i) * 1024 + 512 + h * DH + d0 + tx];
    __syncthreads();
    for (int i = ty; i < 32; i += 8)
        Vt[(size_t)(bh * DH + d0 + i) * NKV + j0 + tx] = tile[tx][i];
}

// ---------- GEMM: C[M][N] = A[M][K] @ Bt[N][K]^T (+bias), 128x128 tile, BK=64 ----------
template <bool AF32, bool OUTF32, bool BIAS>
__global__ __launch_bounds__(256, 2)
void k_gemm(const void* __restrict__ Av, const u16* __restrict__ Bt,
            void* __restrict__ Cv, const float* __restrict__ bias,
            int M, int N, int K) {
    __shared__ u16 lA[128 * 64];
    __shared__ u16 lB[128 * 64];
    const int t = threadIdx.x;
    const int w = t >> 6, lane = t & 63, r = lane & 15, g = lane >> 4;
    const int m0 = blockIdx.x * 128, n0 = blockIdx.y * 128;
    const int wm = (w >> 1) * 64, wn = (w & 1) * 64;

    f32x4 acc[4][4];
#pragma unroll
    for (int a = 0; a < 4; ++a)
#pragma unroll
        for (int c = 0; c < 4; ++c) acc[a][c] = {};

    for (int kt = 0; kt < K; kt += 64) {
        __syncthreads();
        if constexpr (AF32) {
            const float* A = (const float*)Av;
#pragma unroll
            for (int p = 0; p < 4; ++p) {
                int lin = p * 256 + t;
                int row = lin >> 3, ch = lin & 7;
                const float* src = A + (size_t)(m0 + row) * K + kt + ch * 8;
                float4 u0 = *(const float4*)(src);
                float4 u1 = *(const float4*)(src + 4);
                u16x8 v;
                v[0] = f2bf(u0.x); v[1] = f2bf(u0.y); v[2] = f2bf(u0.z); v[3] = f2bf(u0.w);
                v[4] = f2bf(u1.x); v[5] = f2bf(u1.y); v[6] = f2bf(u1.z); v[7] = f2bf(u1.w);
                int byte = ((row << 7) | (ch << 4)) ^ ((row & 7) << 4);
                *(u16x8*)((char*)lA + byte) = v;
            }
        } else {
            const u16* A = (const u16*)Av;
#pragma unroll
            for (int p = 0; p < 4; ++p) {
                int lin = p * 256 + t;
                int row = lin >> 3, ch = lin & 7;
                u16x8 v = *(const u16x8*)(A + (size_t)(m0 + row) * K + kt + ch * 8);
                int byte = ((row << 7) | (ch << 4)) ^ ((row & 7) << 4);
                *(u16x8*)((char*)lA + byte) = v;
            }
        }
#pragma unroll
        for (int p = 0; p < 4; ++p) {
            int lin = p * 256 + t;
            int row = lin >> 3, ch = lin & 7;
            u16x8 v = *(const u16x8*)(Bt + (size_t)(n0 + row) * K + kt + ch * 8);
            int byte = ((row << 7) | (ch << 4)) ^ ((row & 7) << 4);
            *(u16x8*)((char*)lB + byte) = v;
        }
        __syncthreads();
#pragma unroll
        for (int ks = 0; ks < 2; ++ks) {
            bf16x8 af[4], bfr[4];
#pragma unroll
            for (int mt = 0; mt < 4; ++mt) {
                int row = wm + mt * 16 + r;
                int byte = ((row << 7) | (ks << 6) | (g << 4)) ^ ((row & 7) << 4);
                af[mt] = *(const bf16x8*)((const char*)lA + byte);
            }
#pragma unroll
            for (int nt = 0; nt < 4; ++nt) {
                int row = wn + nt * 16 + r;
                int byte = ((row << 7) | (ks << 6) | (g << 4)) ^ ((row & 7) << 4);
                bfr[nt] = *(const bf16x8*)((const char*)lB + byte);
            }
#pragma unroll
            for (int mt = 0; mt < 4; ++mt)
#pragma unroll
                for (int nt = 0; nt < 4; ++nt)
                    acc[mt][nt] = __builtin_amdgcn_mfma_f32_16x16x32_bf16(af[mt], bfr[nt], acc[mt][nt], 0, 0, 0);
        }
    }
#pragma unroll
    for (int mt = 0; mt < 4; ++mt) {
#pragma unroll
        for (int i = 0; i < 4; ++i) {
            int row = m0 + wm + mt * 16 + g * 4 + i;
#pragma unroll
            for (int nt = 0; nt < 4; ++nt) {
                int col = n0 + wn + nt * 16 + r;
                float vv = acc[mt][nt][i];
                if constexpr (BIAS) vv += bias[col];
                if constexpr (OUTF32) ((float*)Cv)[(size_t)row * N + col] = vv;
                else ((u16*)Cv)[(size_t)row * N + col] = f2bf(vv);
            }
        }
    }
}

// ---------- flash attention: Q[b*NQ][512] bf16, KV[b*NKV][1024] bf16 (K cols 0..511),
// Vt[(bh*64+d)][NKV] bf16 -> O[b*NQ][512] bf16 ----------
__global__ __launch_bounds__(256, 2)
void k_attn(const u16* __restrict__ Q, const u16* __restrict__ KV,
            const u16* __restrict__ Vt, u16* __restrict__ O) {
    __shared__ u16 lK[128 * 64];    // [j][d] rows 128B, swz on (row&7)<<4
    __shared__ u16 lV[64 * 128];    // [d][j] rows 256B
    __shared__ u16 lP[128 * 128];   // [i][j] rows 256B
    const int t = threadIdx.x;
    const int w = t >> 6, lane = t & 63, r = lane & 15, g = lane >> 4;
    const int qt = blockIdx.x, bh = blockIdx.y;
    const int b = bh >> 3, h = bh & 7;
    const int q0 = qt * 128;

    // Q fragments in registers: B-operand for S^T = mfma(K, Q)
    bf16x8 qf[2][2];
#pragma unroll
    for (int itl = 0; itl < 2; ++itl) {
        int i = q0 + (w * 2 + itl) * 16 + r;
        const u16* qp = Q + (size_t)(b * NQ + i) * DI + h * DH;
#pragma unroll
        for (int ks = 0; ks < 2; ++ks)
            qf[itl][ks] = *(const bf16x8*)(qp + ks * 32 + g * 8);
    }

    float mrow[2] = {-1e30f, -1e30f};
    float lrow[2] = {0.f, 0.f};
    f32x4 oacc[2][4];
#pragma unroll
    for (int a = 0; a < 2; ++a)
#pragma unroll
        for (int c = 0; c < 4; ++c) oacc[a][c] = {};

    const float scale = 0.125f;

    for (int kv0 = 0; kv0 < NKV; kv0 += 128) {
        __syncthreads();
#pragma unroll
        for (int p = 0; p < 4; ++p) {  // K tile [128][64]
            int lin = p * 256 + t, row = lin >> 3, ch = lin & 7;
            u16x8 v = *(const u16x8*)(KV + (size_t)(b * NKV + kv0 + row) * 1024 + h * DH + ch * 8);
            int byte = ((row << 7) | (ch << 4)) ^ ((row & 7) << 4);
            *(u16x8*)((char*)lK + byte) = v;
        }
#pragma unroll
        for (int p = 0; p < 4; ++p) {  // Vt tile [64][128]
            int lin = p * 256 + t, row = lin >> 4, ch = lin & 15;
            u16x8 v = *(const u16x8*)(Vt + (size_t)(bh * DH + row) * NKV + kv0 + ch * 8);
            int byte = ((row << 8) | (ch << 4)) ^ ((row & 7) << 4);
            *(u16x8*)((char*)lV + byte) = v;
        }
        __syncthreads();

        // S^T = K·Q^T : D[j_local][i] ; lane holds rows j=16jt+4g+ii, col i=16*(2w+itl)+r
        f32x4 st[8][2];
#pragma unroll
        for (int jt = 0; jt < 8; ++jt) {
            bf16x8 kf[2];
#pragma unroll
            for (int ks = 0; ks < 2; ++ks) {
                int row = jt * 16 + r;
                int byte = ((row << 7) | (ks << 6) | (g << 4)) ^ ((row & 7) << 4);
                kf[ks] = *(const bf16x8*)((const char*)lK + byte);
            }
#pragma unroll
            for (int itl = 0; itl < 2; ++itl) {
                f32x4 a = {};
                a = __builtin_amdgcn_mfma_f32_16x16x32_bf16(kf[0], qf[itl][0], a, 0, 0, 0);
                a = __builtin_amdgcn_mfma_f32_16x16x32_bf16(kf[1], qf[itl][1], a, 0, 0, 0);
                st[jt][itl] = a;
            }
        }

        // online softmax per q-row (each lane owns row i = 16*(2w+itl)+r jointly with its 3 g-peers)
        float corr[2];
#pragma unroll
        for (int itl = 0; itl < 2; ++itl) {
            float mx = -1e30f;
#pragma unroll
            for (int jt = 0; jt < 8; ++jt)
#pragma unroll
                for (int ii = 0; ii < 4; ++ii) mx = fmaxf(mx, st[jt][itl][ii]);
            mx = fmaxf(mx, __shfl_xor(mx, 16));
            mx = fmaxf(mx, __shfl_xor(mx, 32));
            float mnew = fmaxf(mrow[itl], mx * scale);
            corr[itl] = __expf(mrow[itl] - mnew);
            mrow[itl] = mnew;
            float sum = 0.f;
            int i = (w * 2 + itl) * 16 + r;
#pragma unroll
            for (int jt = 0; jt < 8; ++jt) {
                u16x4 pk;
#pragma unroll
                for (int ii = 0; ii < 4; ++ii) {
                    float e = __expf(st[jt][itl][ii] * scale - mnew);
                    sum += e;
                    pk[ii] = f2bf(e);
                }
                // P[i][16jt+4g + ii] : 8B contiguous write
                int byte = ((i << 8) + jt * 32 + g * 8) ^ ((i & 7) << 4);
                *(u16x4*)((char*)lP + byte) = pk;
            }
            sum += __shfl_xor(sum, 16);
            sum += __shfl_xor(sum, 32);
            lrow[itl] = lrow[itl] * corr[itl] + sum;
        }

        // rescale O accumulator: O rows i = 16*(2w+mtl) + 4g + ii; corr lives at lane (4g+ii)
#pragma unroll
        for (int mtl = 0; mtl < 2; ++mtl) {
#pragma unroll
            for (int ii = 0; ii < 4; ++ii) {
                float c = __shfl(corr[mtl], g * 4 + ii);
#pragma unroll
                for (int nt = 0; nt < 4; ++nt) oacc[mtl][nt][ii] *= c;
            }
        }

        // PV: O[i][d] += P[i][j] * V[j][d]; A from lP (own wave's rows), B from lV
#pragma unroll
        for (int ks = 0; ks < 4; ++ks) {
            bf16x8 vf[4], pf[2];
#pragma unroll
            for (int nt = 0; nt < 4; ++nt) {
                int row = nt * 16 + r;
                int byte = ((row << 8) | (ks << 6) | (g << 4)) ^ ((row & 7) << 4);
                vf[nt] = *(const bf16x8*)((const char*)lV + byte);
            }
#pragma unroll
            for (int mtl = 0; mtl < 2; ++mtl) {
                int row = (w * 2 + mtl) * 16 + r;
                int byte = ((row << 8) | (ks << 6) | (g << 4)) ^ ((row & 7) << 4);
                pf[mtl] = *(const bf16x8*)((const char*)lP + byte);
            }
#pragma unroll
            for (int mtl = 0; mtl < 2; ++mtl)
#pragma unroll
                for (int nt = 0; nt < 4; ++nt)
                    oacc[mtl][nt] = __builtin_amdgcn_mfma_f32_16x16x32_bf16(pf[mtl], vf[nt], oacc[mtl][nt], 0, 0, 0);
        }
    }

    // normalize + write O (bf16)
#pragma unroll
    for (int mtl = 0; mtl < 2; ++mtl) {
#pragma unroll
        for (int ii = 0; ii < 4; ++ii) {
            float lv = __shfl(lrow[mtl], g * 4 + ii);
            float linv = 1.f / lv;
            int i = q0 + (w * 2 + mtl) * 16 + g * 4 + ii;
#pragma unroll
            for (int nt = 0; nt < 4; ++nt) {
                int d = nt * 16 + r;
                O[(size_t)(b * NQ + i) * DI + h * DH + d] = f2bf(oacc[mtl][nt][ii] * linv);
            }
        }
    }
}

extern "C" void kernel_launch(void* const* d_in, const int* in_sizes, int n_in,
                              void* d_out, int out_size, void* d_ws, size_t ws_size,
                              hipStream_t stream) {
    (void)in_sizes; (void)n_in; (void)out_size; (void)ws_size;
    const float* x   = (const float*)d_in[0];
    const float* ctx = (const float*)d_in[1];
    const float* Wq  = (const float*)d_in[2];
    const float* Wk  = (const float*)d_in[3];
    const float* Wv  = (const float*)d_in[4];
    const float* Wo  = (const float*)d_in[5];
    const float* bo  = (const float*)d_in[6];
    float* out = (float*)d_out;

    char* ws = (char*)d_ws;
    u16* Wqt  = (u16*)(ws);
    u16* Wkvt = (u16*)(ws + (size_t)512 * 512 * 2);
    u16* Wot  = (u16*)(ws + (size_t)512 * 512 * 2 + (size_t)1024 * 768 * 2);
    char* p = ws + (size_t)512 * 512 * 2 + (size_t)1024 * 768 * 2 + (size_t)512 * 512 * 2;
    u16* Qw  = (u16*)p;  p += (size_t)BB * NQ * DI * 2;       // 16 MB
    u16* KVw = (u16*)p;  p += (size_t)BB * NKV * 1024 * 2;    // 8 MB
    u16* Vtw = (u16*)p;  p += (size_t)BB * NH * DH * NKV * 2; // 4 MB
    u16* Ow  = (u16*)p;                                       // 16 MB

    k_transposeW<<<dim3(16, 16), 256, 0, stream>>>(Wq, Wqt, 512, 512);
    k_transposeW<<<dim3(24, 16), 256, 0, stream>>>(Wk, Wkvt, 768, 512);
    k_transposeW<<<dim3(24, 16), 256, 0, stream>>>(Wv, Wkvt + (size_t)512 * 768, 768, 512);
    k_transposeW<<<dim3(16, 16), 256, 0, stream>>>(Wo, Wot, 512, 512);

    k_gemm<true, false, false><<<dim3(128, 4), 256, 0, stream>>>(x, Wqt, Qw, nullptr, BB * NQ, DI, QD);
    k_gemm<true, false, false><<<dim3(32, 8), 256, 0, stream>>>(ctx, Wkvt, KVw, nullptr, BB * NKV, 1024, CD);
    k_transposeV<<<dim3(32, 2, 32), 256, 0, stream>>>(KVw, Vtw);
    k_attn<<<dim3(32, 32), 256, 0, stream>>>(Qw, KVw, Vtw, Ow);
    k_gemm<false, true, true><<<dim3(128, 4), 256, 0, stream>>>(Ow, Wot, out, bo, BB * NQ, QD, DI);
}